// Round 1
// baseline (50544.421 us; speedup 1.0000x reference)
//
#include <hip/hip_runtime.h>
#include <math.h>
#include <stdint.h>

#define NB 16
#define NN 50000
#define NC 8
#define ND 2
#define MAX_DET 300
#define NMS_T 0.5f
#define SCORE_T 0.05f

__device__ __forceinline__ float neg_inf() { return -__builtin_inff(); }

// ---------------- Kernel 1: per-(b,c) greedy NMS -------------------------
// One block per bc = b*NC + c. mask is block-private [bc][NN] bytes.
__global__ __launch_bounds__(256) void nms_kernel(
    const float* __restrict__ boxes,      // [B,N,4]
    const float* __restrict__ cls,        // [B,N,C]
    unsigned char* __restrict__ mask,     // [B*C, N]
    int* __restrict__ sel_idx,            // [B*C, MAX_DET]
    float* __restrict__ sel_score)        // [B*C, MAX_DET]
{
    const int bc = blockIdx.x;
    const int b = bc / NC, c = bc % NC;
    const int tid = threadIdx.x;
    const float4* bx4 = (const float4*)(boxes + (size_t)b * NN * 4);
    const float* sc = cls + (size_t)b * NN * NC + c;
    unsigned char* mk = mask + (size_t)bc * NN;
    int* si = sel_idx + bc * MAX_DET;
    float* ss = sel_score + bc * MAX_DET;

    // init block-private mask (harness poisons ws; must be deterministic)
    for (int n = tid; n < NN; n += 256) mk[n] = 0;
    __syncthreads();

    __shared__ float rv[256];
    __shared__ int   ri[256];
    __shared__ float sbox[4];

    for (int k = 0; k < MAX_DET; ++k) {
        // ---- argmax over active candidates, lowest-index tie-break ----
        float bv = neg_inf(); int bi = 0x7fffffff;
        for (int n = tid; n < NN; n += 256) {
            if (!mk[n]) {
                float v = sc[(size_t)n * NC];
                if (v > SCORE_T && v > bv) { bv = v; bi = n; }  // strict > keeps lowest n per thread
            }
        }
        rv[tid] = bv; ri[tid] = bi;
        __syncthreads();
        for (int s = 128; s > 0; s >>= 1) {
            if (tid < s) {
                float ov = rv[tid + s]; int oi = ri[tid + s];
                if (ov > rv[tid] || (ov == rv[tid] && oi < ri[tid])) { rv[tid] = ov; ri[tid] = oi; }
            }
            __syncthreads();
        }
        float mval = rv[0]; int midx = ri[0];

        if (mval == neg_inf()) {          // exhausted: remaining slots invalid
            for (int kk = k + tid; kk < MAX_DET; kk += 256) { si[kk] = 0; ss[kk] = neg_inf(); }
            break;                         // uniform branch (rv[0] shared)
        }
        if (tid == 0) {
            si[k] = midx; ss[k] = mval;
            float4 sb = bx4[midx];
            sbox[0] = sb.x; sbox[1] = sb.y; sbox[2] = sb.z; sbox[3] = sb.w;
        }
        __syncthreads();
        float ax1 = sbox[0], ay1 = sbox[1], ax2 = sbox[2], ay2 = sbox[3];
        // exact op order of reference; _rn intrinsics forbid FMA contraction
        float area_a = __fmul_rn(__fsub_rn(ax2, ax1), __fsub_rn(ay2, ay1));
        for (int n = tid; n < NN; n += 256) {
            float4 bb = bx4[n];
            float x1 = fmaxf(ax1, bb.x), y1 = fmaxf(ay1, bb.y);
            float x2 = fminf(ax2, bb.z), y2 = fminf(ay2, bb.w);
            float inter = __fmul_rn(fmaxf(__fsub_rn(x2, x1), 0.0f),
                                    fmaxf(__fsub_rn(y2, y1), 0.0f));
            float area_b = __fmul_rn(__fsub_rn(bb.z, bb.x), __fsub_rn(bb.w, bb.y));
            float uni = __fsub_rn(__fadd_rn(area_a, area_b), inter);
            float iou = __fdiv_rn(inter, fmaxf(uni, 1e-8f));
            if (iou > NMS_T) mk[n] = 1;   // includes midx itself (iou == 1)
        }
        __syncthreads();
    }
}

// ---------------- Kernel 2: per-image top-300 + gather -------------------
// key = (monotone(score) << 32) | ~candIdx  -> sort descending gives
// (score desc, candIdx asc) == lax.top_k tie-breaking.
__global__ __launch_bounds__(256) void topk_kernel(
    const float* __restrict__ boxes,      // [B,N,4]
    const float* __restrict__ other,      // [B,N,D]
    const int* __restrict__ sel_idx,      // [B*C, MAX_DET]
    const float* __restrict__ sel_score,  // [B*C, MAX_DET]
    float* __restrict__ out)
{
    const int b = blockIdx.x;
    const int tid = threadIdx.x;
    const int NCAND = NC * MAX_DET;       // 2400
    __shared__ unsigned long long keys[4096];

    for (int m = tid; m < 4096; m += 256) {
        unsigned long long key = 0ull;    // padding sorts last, decodes invalid
        if (m < NCAND) {
            float v = sel_score[b * NCAND + m];
            unsigned u = __float_as_uint(v);
            u ^= (u & 0x80000000u) ? 0xFFFFFFFFu : 0x80000000u;
            key = ((unsigned long long)u << 32) | (unsigned)(~(unsigned)m);
        }
        keys[m] = key;
    }
    __syncthreads();

    for (int k = 2; k <= 4096; k <<= 1) {
        for (int j = k >> 1; j > 0; j >>= 1) {
            for (int i = tid; i < 4096; i += 256) {
                int ixj = i ^ j;
                if (ixj > i) {
                    bool dir = ((i & k) == 0);    // descending overall
                    unsigned long long a = keys[i], bq = keys[ixj];
                    if ((a < bq) == dir) { keys[i] = bq; keys[ixj] = a; }
                }
            }
            __syncthreads();
        }
    }

    const float4* bx4 = (const float4*)(boxes + (size_t)b * NN * 4);
    const float*  ot  = other + (size_t)b * NN * ND;
    float* ob = out;                                  // [B,300,4]
    float* os = out + NB * MAX_DET * 4;               // [B,300]
    float* ol = os + NB * MAX_DET;                    // [B,300] labels as float
    float* oo = ol + NB * MAX_DET;                    // [B,300,2]

    for (int k = tid; k < MAX_DET; k += 256) {
        unsigned long long key = keys[k];
        unsigned u = (unsigned)(key >> 32);
        unsigned uo = (u & 0x80000000u) ? (u ^ 0x80000000u) : (u ^ 0xFFFFFFFFu);
        float score = __uint_as_float(uo);
        bool valid = isfinite(score);     // -inf survivors & NaN padding -> invalid
        float b0=-1.f,b1=-1.f,b2=-1.f,b3=-1.f,scv=-1.f,lab=-1.f,o0=-1.f,o1=-1.f;
        if (valid) {
            int m = (int)(~(unsigned)key);
            int c = m / MAX_DET, slot = m - c * MAX_DET;
            int n = sel_idx[(b * NC + c) * MAX_DET + slot];
            float4 bb = bx4[n];
            b0 = bb.x; b1 = bb.y; b2 = bb.z; b3 = bb.w;
            scv = score; lab = (float)c;
            o0 = ot[n * ND + 0]; o1 = ot[n * ND + 1];
        }
        int base = b * MAX_DET + k;
        ob[base * 4 + 0] = b0; ob[base * 4 + 1] = b1;
        ob[base * 4 + 2] = b2; ob[base * 4 + 3] = b3;
        os[base] = scv; ol[base] = lab;
        oo[base * 2 + 0] = o0; oo[base * 2 + 1] = o1;
    }
}

extern "C" void kernel_launch(void* const* d_in, const int* in_sizes, int n_in,
                              void* d_out, int out_size, void* d_ws, size_t ws_size,
                              hipStream_t stream) {
    const float* boxes = (const float*)d_in[0];
    const float* cls   = (const float*)d_in[1];
    const float* other = (const float*)d_in[2];
    float* out = (float*)d_out;

    // ws layout: mask [B*C*N] bytes | sel_idx [B*C*300] i32 | sel_score [B*C*300] f32
    unsigned char* mask = (unsigned char*)d_ws;
    char* p = (char*)d_ws + (size_t)NB * NC * NN;          // 6,400,000 (16B aligned)
    int* sel_idx = (int*)p;
    float* sel_score = (float*)(p + (size_t)NB * NC * MAX_DET * sizeof(int));

    nms_kernel<<<NB * NC, 256, 0, stream>>>(boxes, cls, mask, sel_idx, sel_score);
    topk_kernel<<<NB, 256, 0, stream>>>(boxes, other, sel_idx, sel_score, out);
}

// Round 2
// 699.019 us; speedup vs baseline: 72.3077x; 72.3077x over previous
//
#include <hip/hip_runtime.h>
#include <math.h>
#include <stdint.h>

#define NB 16
#define NN 50000
#define NC 8
#define ND 2
#define MAX_DET 300
#define NMS_T 0.5f
#define SCORE_T 0.05f
#define CAP 4096
#define TARGET 2048

__device__ __forceinline__ float neg_inf() { return -__builtin_inff(); }

// IoU in the reference's exact op order. A = previously-selected box ("box"),
// B = candidate ("boxes[n]"). _rn intrinsics forbid FMA contraction.
__device__ __forceinline__ float iou_ref(float ax1, float ay1, float ax2, float ay2,
                                         float area_a,
                                         float bx1, float by1, float bx2, float by2) {
    float x1 = fmaxf(ax1, bx1), y1 = fmaxf(ay1, by1);
    float x2 = fminf(ax2, bx2), y2 = fminf(ay2, by2);
    float inter = __fmul_rn(fmaxf(__fsub_rn(x2, x1), 0.0f),
                            fmaxf(__fsub_rn(y2, y1), 0.0f));
    float area_b = __fmul_rn(__fsub_rn(bx2, bx1), __fsub_rn(by2, by1));
    float uni = __fsub_rn(__fadd_rn(area_a, area_b), inter);
    return __fdiv_rn(inter, fmaxf(uni, 1e-8f));
}

// ---------------- Kernel 1: per-(b,c) greedy NMS (sorted-candidate fast path) ----
__global__ __launch_bounds__(256) void nms_fast(
    const float* __restrict__ boxes,      // [B,N,4]
    const float* __restrict__ cls,        // [B,N,C]
    unsigned char* __restrict__ mask_ws,  // [B*C, N] (fallback only)
    int* __restrict__ sel_idx,            // [B*C, MAX_DET]
    float* __restrict__ sel_score)        // [B*C, MAX_DET]
{
    const int bc = blockIdx.x;
    const int b = bc / NC, c = bc % NC;
    const int tid = threadIdx.x;
    const float4* bx4 = (const float4*)(boxes + (size_t)b * NN * 4);
    const float* sc = cls + (size_t)b * NN * NC + c;
    unsigned char* mk = mask_ws + (size_t)bc * NN;
    int* si = sel_idx + bc * MAX_DET;
    float* ss = sel_score + bc * MAX_DET;

    __shared__ unsigned long long keys[CAP];   // 32 KB
    __shared__ int hist[256];
    __shared__ float4 abox[MAX_DET];
    __shared__ float aarea[MAX_DET];
    __shared__ int sh_cnt, sh_cut, sh_total;
    __shared__ float rv[256];
    __shared__ int   ri[256];
    __shared__ float sboxsh[5];                // fallback selected box + area

    // ---- pass 1: histogram of scores > SCORE_T (uniform[0,1] -> linear bins) ----
    hist[tid] = 0;
    __syncthreads();
    for (int n = tid; n < NN; n += 256) {
        float v = sc[(size_t)n * NC];
        if (v > SCORE_T) {
            int bn = (int)(v * 256.0f); bn = bn > 255 ? 255 : bn;
            atomicAdd(&hist[bn], 1);
        }
    }
    __syncthreads();
    if (tid == 0) {
        int total = 0;
        for (int bn = 0; bn < 256; ++bn) total += hist[bn];
        int suff = 0, cut = 0;
        for (int bn = 255; bn >= 0; --bn) {
            suff += hist[bn];
            if (suff >= TARGET) { cut = bn; break; }
        }
        sh_cut = cut; sh_total = total; sh_cnt = 0;
    }
    __syncthreads();
    const int cut = sh_cut;

    // ---- pass 2: compact candidates with bin >= cut into LDS keys ----
    for (int n = tid; n < NN; n += 256) {
        float v = sc[(size_t)n * NC];
        if (v > SCORE_T) {
            int bn = (int)(v * 256.0f); bn = bn > 255 ? 255 : bn;
            if (bn >= cut) {
                int p = atomicAdd(&sh_cnt, 1);
                if (p < CAP) {
                    unsigned u = __float_as_uint(v);
                    u ^= (u & 0x80000000u) ? 0xFFFFFFFFu : 0x80000000u;
                    keys[p] = ((unsigned long long)u << 32) | (unsigned)(~(unsigned)n);
                }
            }
        }
    }
    __syncthreads();
    const int cnt = sh_cnt, total = sh_total;
    const bool full_fb = (cnt > CAP);          // dropped high-score candidates -> redo exactly
    const int inSet = cnt < CAP ? cnt : CAP;
    for (int i = inSet + tid; i < CAP; i += 256) keys[i] = 0ull;  // pad sorts last
    __syncthreads();

    int n_acc = 0;
    if (!full_fb) {
        // ---- bitonic sort CAP keys descending: (score desc, idx asc) ----
        for (int k = 2; k <= CAP; k <<= 1) {
            for (int j = k >> 1; j > 0; j >>= 1) {
                for (int i = tid; i < CAP; i += 256) {
                    int ixj = i ^ j;
                    if (ixj > i) {
                        bool dir = ((i & k) == 0);
                        unsigned long long a = keys[i], bq = keys[ixj];
                        if ((a < bq) == dir) { keys[i] = bq; keys[ixj] = a; }
                    }
                }
                __syncthreads();
            }
        }

        // ---- sequential greedy accept-scan ----
        for (int k = 0; k < CAP; ++k) {
            if (n_acc == MAX_DET) break;               // uniform
            unsigned long long key = keys[k];
            if (key == 0ull) break;                    // padding: exhausted (uniform)
            int idx = (int)(~(unsigned)key);
            unsigned u = (unsigned)(key >> 32);
            unsigned uo = (u & 0x80000000u) ? (u ^ 0x80000000u) : (~u);
            float score = __uint_as_float(uo);
            float4 bb = bx4[idx];                      // broadcast load
            float area_b = __fmul_rn(__fsub_rn(bb.z, bb.x), __fsub_rn(bb.w, bb.y));
            int sup = 0;
            for (int t = tid; t < n_acc; t += 256) {
                float4 A = abox[t];
                float iou = iou_ref(A.x, A.y, A.z, A.w, aarea[t], bb.x, bb.y, bb.z, bb.w);
                if (iou > NMS_T) sup = 1;
            }
            sup = __syncthreads_or(sup);
            if (!sup) {                                // uniform
                if (tid == 0) {
                    abox[n_acc] = bb; aarea[n_acc] = area_b;
                    si[n_acc] = idx; ss[n_acc] = score;
                }
                n_acc++;
                __syncthreads();                       // make abox visible
            }
        }
    }

    const bool part_fb = (!full_fb) && (n_acc < MAX_DET) && (total > inSet);

    if (full_fb || part_fb) {
        // ======== exact fallback: mask-based argmax loop (round-0 algorithm) ======
        if (full_fb) {
            n_acc = 0;
            for (int n = tid; n < NN; n += 256) mk[n] = 0;
        } else {
            // mask = suppressed by any accepted box
            for (int n = tid; n < NN; n += 256) {
                float4 bbn = bx4[n];
                int s = 0;
                for (int t = 0; t < n_acc; ++t) {
                    float4 A = abox[t];
                    float iou = iou_ref(A.x, A.y, A.z, A.w, aarea[t],
                                        bbn.x, bbn.y, bbn.z, bbn.w);
                    if (iou > NMS_T) s = 1;
                }
                mk[n] = (unsigned char)s;
            }
        }
        __syncthreads();

        for (int k = n_acc; k < MAX_DET; ++k) {
            float bv = neg_inf(); int bi = 0x7fffffff;
            for (int n = tid; n < NN; n += 256) {
                if (!mk[n]) {
                    float v = sc[(size_t)n * NC];
                    if (v > SCORE_T && v > bv) { bv = v; bi = n; }
                }
            }
            rv[tid] = bv; ri[tid] = bi;
            __syncthreads();
            for (int s = 128; s > 0; s >>= 1) {
                if (tid < s) {
                    float ov = rv[tid + s]; int oi = ri[tid + s];
                    if (ov > rv[tid] || (ov == rv[tid] && oi < ri[tid])) { rv[tid] = ov; ri[tid] = oi; }
                }
                __syncthreads();
            }
            float mval = rv[0]; int midx = ri[0];
            if (mval == neg_inf()) {
                for (int kk = k + tid; kk < MAX_DET; kk += 256) { si[kk] = 0; ss[kk] = neg_inf(); }
                break;
            }
            if (tid == 0) {
                si[k] = midx; ss[k] = mval;
                float4 sb = bx4[midx];
                sboxsh[0] = sb.x; sboxsh[1] = sb.y; sboxsh[2] = sb.z; sboxsh[3] = sb.w;
                sboxsh[4] = __fmul_rn(__fsub_rn(sb.z, sb.x), __fsub_rn(sb.w, sb.y));
            }
            __syncthreads();
            float ax1 = sboxsh[0], ay1 = sboxsh[1], ax2 = sboxsh[2], ay2 = sboxsh[3];
            float area_a = sboxsh[4];
            for (int n = tid; n < NN; n += 256) {
                float4 bbn = bx4[n];
                float iou = iou_ref(ax1, ay1, ax2, ay2, area_a, bbn.x, bbn.y, bbn.z, bbn.w);
                if (iou > NMS_T) mk[n] = 1;
            }
            __syncthreads();
        }
    } else {
        // exhausted legitimately (or filled 300): pad remaining slots
        for (int kk = n_acc + tid; kk < MAX_DET; kk += 256) { si[kk] = 0; ss[kk] = neg_inf(); }
    }
}

// ---------------- Kernel 2: per-image top-300 + gather (unchanged) -------
__global__ __launch_bounds__(256) void topk_kernel(
    const float* __restrict__ boxes,
    const float* __restrict__ other,
    const int* __restrict__ sel_idx,
    const float* __restrict__ sel_score,
    float* __restrict__ out)
{
    const int b = blockIdx.x;
    const int tid = threadIdx.x;
    const int NCAND = NC * MAX_DET;       // 2400
    __shared__ unsigned long long keys[4096];

    for (int m = tid; m < 4096; m += 256) {
        unsigned long long key = 0ull;
        if (m < NCAND) {
            float v = sel_score[b * NCAND + m];
            unsigned u = __float_as_uint(v);
            u ^= (u & 0x80000000u) ? 0xFFFFFFFFu : 0x80000000u;
            key = ((unsigned long long)u << 32) | (unsigned)(~(unsigned)m);
        }
        keys[m] = key;
    }
    __syncthreads();

    for (int k = 2; k <= 4096; k <<= 1) {
        for (int j = k >> 1; j > 0; j >>= 1) {
            for (int i = tid; i < 4096; i += 256) {
                int ixj = i ^ j;
                if (ixj > i) {
                    bool dir = ((i & k) == 0);
                    unsigned long long a = keys[i], bq = keys[ixj];
                    if ((a < bq) == dir) { keys[i] = bq; keys[ixj] = a; }
                }
            }
            __syncthreads();
        }
    }

    const float4* bx4 = (const float4*)(boxes + (size_t)b * NN * 4);
    const float*  ot  = other + (size_t)b * NN * ND;
    float* ob = out;
    float* os = out + NB * MAX_DET * 4;
    float* ol = os + NB * MAX_DET;
    float* oo = ol + NB * MAX_DET;

    for (int k = tid; k < MAX_DET; k += 256) {
        unsigned long long key = keys[k];
        unsigned u = (unsigned)(key >> 32);
        unsigned uo = (u & 0x80000000u) ? (u ^ 0x80000000u) : (u ^ 0xFFFFFFFFu);
        float score = __uint_as_float(uo);
        bool valid = isfinite(score);
        float b0=-1.f,b1=-1.f,b2=-1.f,b3=-1.f,scv=-1.f,lab=-1.f,o0=-1.f,o1=-1.f;
        if (valid) {
            int m = (int)(~(unsigned)key);
            int c = m / MAX_DET, slot = m - c * MAX_DET;
            int n = sel_idx[(b * NC + c) * MAX_DET + slot];
            float4 bb = bx4[n];
            b0 = bb.x; b1 = bb.y; b2 = bb.z; b3 = bb.w;
            scv = score; lab = (float)c;
            o0 = ot[n * ND + 0]; o1 = ot[n * ND + 1];
        }
        int base = b * MAX_DET + k;
        ob[base * 4 + 0] = b0; ob[base * 4 + 1] = b1;
        ob[base * 4 + 2] = b2; ob[base * 4 + 3] = b3;
        os[base] = scv; ol[base] = lab;
        oo[base * 2 + 0] = o0; oo[base * 2 + 1] = o1;
    }
}

extern "C" void kernel_launch(void* const* d_in, const int* in_sizes, int n_in,
                              void* d_out, int out_size, void* d_ws, size_t ws_size,
                              hipStream_t stream) {
    const float* boxes = (const float*)d_in[0];
    const float* cls   = (const float*)d_in[1];
    const float* other = (const float*)d_in[2];
    float* out = (float*)d_out;

    unsigned char* mask = (unsigned char*)d_ws;
    char* p = (char*)d_ws + (size_t)NB * NC * NN;
    int* sel_idx = (int*)p;
    float* sel_score = (float*)(p + (size_t)NB * NC * MAX_DET * sizeof(int));

    nms_fast<<<NB * NC, 256, 0, stream>>>(boxes, cls, mask, sel_idx, sel_score);
    topk_kernel<<<NB, 256, 0, stream>>>(boxes, other, sel_idx, sel_score, out);
}

// Round 3
// 268.259 us; speedup vs baseline: 188.4168x; 2.6058x over previous
//
#include <hip/hip_runtime.h>
#include <math.h>
#include <stdint.h>

#define NB 16
#define NN 50000
#define NC 8
#define ND 2
#define MAX_DET 300
#define NMS_T 0.5f
#define SCORE_T 0.05f
#define CAP 4096
#define TARGET 2048
#define CHUNK 256
#define NT 512

typedef unsigned long long u64;

__device__ __forceinline__ float neg_inf() { return -__builtin_inff(); }

// IoU in the reference's exact op order (symmetric, but keep orientation anyway).
__device__ __forceinline__ float iou_ref(float ax1, float ay1, float ax2, float ay2,
                                         float area_a,
                                         float bx1, float by1, float bx2, float by2) {
    float x1 = fmaxf(ax1, bx1), y1 = fmaxf(ay1, by1);
    float x2 = fminf(ax2, bx2), y2 = fminf(ay2, by2);
    float inter = __fmul_rn(fmaxf(__fsub_rn(x2, x1), 0.0f),
                            fmaxf(__fsub_rn(y2, y1), 0.0f));
    float area_b = __fmul_rn(__fsub_rn(bx2, bx1), __fsub_rn(by2, by1));
    float uni = __fsub_rn(__fadd_rn(area_a, area_b), inter);
    return __fdiv_rn(inter, fmaxf(uni, 1e-8f));
}

__global__ __launch_bounds__(NT) void nms_fast(
    const float* __restrict__ boxes,      // [B,N,4]
    const float* __restrict__ cls,        // [B,N,C]
    unsigned char* __restrict__ mask_ws,  // [B*C, N] (fallback only)
    int* __restrict__ sel_idx,            // [B*C, MAX_DET]
    float* __restrict__ sel_score)        // [B*C, MAX_DET]
{
    const int bc = blockIdx.x;
    const int b = bc / NC, c = bc % NC;
    const int tid = threadIdx.x;
    const float4* bx4 = (const float4*)(boxes + (size_t)b * NN * 4);
    const float* sc = cls + (size_t)b * NN * NC + c;
    unsigned char* mk = mask_ws + (size_t)bc * NN;
    int* si = sel_idx + bc * MAX_DET;
    float* ss = sel_score + bc * MAX_DET;

    __shared__ u64 keys[CAP];                  // 32 KB
    __shared__ u64 M[4][CHUNK];                // 8 KB  (M[w][i]: bank-friendly)
    __shared__ float4 cbox[CHUNK];             // 4 KB
    __shared__ float carea[CHUNK];
    __shared__ int   cidx[CHUNK];
    __shared__ float cscore[CHUNK];
    __shared__ unsigned presup[CHUNK];
    __shared__ u64 accmask_s[4];
    __shared__ float4 abox[MAX_DET];           // 4.8 KB
    __shared__ float aarea[MAX_DET];
    __shared__ int hist[256];
    __shared__ int sh_cnt, sh_cut, sh_total;
    __shared__ float rv[NT];                   // fallback reduce
    __shared__ int   ri[NT];
    __shared__ float sboxsh[5];

    // ---- pass 1: histogram of scores > SCORE_T ----
    if (tid < 256) hist[tid] = 0;
    __syncthreads();
    for (int n = tid; n < NN; n += NT) {
        float v = sc[(size_t)n * NC];
        if (v > SCORE_T) {
            int bn = (int)(v * 256.0f); bn = bn > 255 ? 255 : bn;
            atomicAdd(&hist[bn], 1);
        }
    }
    __syncthreads();
    if (tid == 0) {
        int total = 0;
        for (int bn = 0; bn < 256; ++bn) total += hist[bn];
        int suff = 0, cut = 0;
        for (int bn = 255; bn >= 0; --bn) {
            suff += hist[bn];
            if (suff >= TARGET) { cut = bn; break; }
        }
        sh_cut = cut; sh_total = total; sh_cnt = 0;
    }
    __syncthreads();
    const int cut = sh_cut;

    // ---- pass 2: compact candidates with bin >= cut into LDS keys ----
    for (int n = tid; n < NN; n += NT) {
        float v = sc[(size_t)n * NC];
        if (v > SCORE_T) {
            int bn = (int)(v * 256.0f); bn = bn > 255 ? 255 : bn;
            if (bn >= cut) {
                int p = atomicAdd(&sh_cnt, 1);
                if (p < CAP) {
                    unsigned u = __float_as_uint(v);
                    u ^= (u & 0x80000000u) ? 0xFFFFFFFFu : 0x80000000u;
                    keys[p] = ((u64)u << 32) | (unsigned)(~(unsigned)n);
                }
            }
        }
    }
    __syncthreads();
    const int cnt = sh_cnt, total = sh_total;
    const bool full_fb = (cnt > CAP);
    const int inSet = cnt < CAP ? cnt : CAP;
    for (int i = inSet + tid; i < CAP; i += NT) keys[i] = 0ull;  // pad sorts last
    __syncthreads();

    int n_acc = 0;
    if (!full_fb) {
        // ---- bitonic sort, all-lanes-active pair indexing ----
        for (int k = 2; k <= CAP; k <<= 1) {
            for (int j = k >> 1; j > 0; j >>= 1) {
                for (int p = tid; p < CAP / 2; p += NT) {
                    int i = 2 * p - (p & (j - 1));
                    int ix = i + j;
                    bool dir = ((i & k) == 0);          // descending overall
                    u64 a = keys[i], bq = keys[ix];
                    if ((a < bq) == dir) { keys[i] = bq; keys[ix] = a; }
                }
                __syncthreads();
            }
        }

        // ---- chunked matrix greedy accept ----
        int base = 0;
        while (n_acc < MAX_DET && base < inSet) {
            int m = inSet - base; if (m > CHUNK) m = CHUNK;

            // load chunk (parallel gather)
            if (tid < CHUNK) {
                if (tid < m) {
                    u64 key = keys[base + tid];
                    int idx = (int)(~(unsigned)key);
                    unsigned u = (unsigned)(key >> 32);
                    unsigned uo = (u & 0x80000000u) ? (u ^ 0x80000000u) : (~u);
                    float4 bb = bx4[idx];
                    cbox[tid] = bb;
                    carea[tid] = __fmul_rn(__fsub_rn(bb.z, bb.x), __fsub_rn(bb.w, bb.y));
                    cidx[tid] = idx; cscore[tid] = __uint_as_float(uo);
                    presup[tid] = 0u;
                } else presup[tid] = 1u;
            }
            __syncthreads();

            // pre-suppression vs accepted list + intra-chunk IoU matrix
            {
                int i = tid & (CHUNK - 1);
                int half = tid >> 8;                   // 0 or 1
                if (i < m) {
                    float4 B = cbox[i];
                    unsigned p = 0;
                    for (int t = half; t < n_acc; t += 2) {
                        float4 A = abox[t];
                        if (iou_ref(A.x, A.y, A.z, A.w, aarea[t],
                                    B.x, B.y, B.z, B.w) > NMS_T) { p = 1; break; }
                    }
                    if (p) atomicOr(&presup[i], 1u);
                    // matrix words: half 0 -> w=0,1 ; half 1 -> w=2,3
                    for (int w = half * 2; w < half * 2 + 2; ++w) {
                        u64 bits = 0;
                        int j0 = w * 64;
                        for (int jj = 0; jj < 64; ++jj) {
                            int j = j0 + jj;
                            if (j < m && j != i) {
                                float4 A = cbox[j];
                                if (iou_ref(A.x, A.y, A.z, A.w, carea[j],
                                            B.x, B.y, B.z, B.w) > NMS_T)
                                    bits |= 1ull << jj;
                            }
                        }
                        M[w][i] = bits;
                    }
                }
            }
            __syncthreads();

            // wave-0 greedy resolve, all in registers
            if (tid < 64) {
                u64 a0 = 0, a1 = 0, a2 = 0, a3 = 0;
                int ngroups = (m + 63) >> 6;
                for (int g = 0; g < ngroups; ++g) {
                    int i = g * 64 + tid;
                    unsigned pe = 1; u64 mg = 0;
                    if (i < m) {
                        pe = presup[i];
                        mg = M[g][i];
                        u64 fold = 0;
                        if (g > 0) fold |= M[0][i] & a0;
                        if (g > 1) fold |= M[1][i] & a1;
                        if (g > 2) fold |= M[2][i] & a2;
                        if (fold) pe = 1;
                    }
                    u64 accw = 0;
                    for (int l = 0; l < 64; ++l) {
                        u64 mgl = __shfl(mg, l, 64);
                        unsigned pel = __shfl(pe, l, 64);
                        if (!pel && (mgl & accw) == 0ull) accw |= 1ull << l;
                    }
                    if (g == 0) a0 = accw; else if (g == 1) a1 = accw;
                    else if (g == 2) a2 = accw; else a3 = accw;
                }
                if (tid == 0) {
                    accmask_s[0] = a0; accmask_s[1] = a1;
                    accmask_s[2] = a2; accmask_s[3] = a3;
                }
            }
            __syncthreads();

            // rank + append accepted (truncate at MAX_DET)
            u64 a0 = accmask_s[0], a1 = accmask_s[1], a2 = accmask_s[2], a3 = accmask_s[3];
            int add = __popcll(a0) + __popcll(a1) + __popcll(a2) + __popcll(a3);
            if (tid < m) {
                int g = tid >> 6, o = tid & 63;
                u64 aw = (g == 0) ? a0 : (g == 1) ? a1 : (g == 2) ? a2 : a3;
                if ((aw >> o) & 1ull) {
                    int rank = 0;
                    if (g > 0) rank += __popcll(a0);
                    if (g > 1) rank += __popcll(a1);
                    if (g > 2) rank += __popcll(a2);
                    rank += __popcll(aw & ((1ull << o) - 1ull));
                    int pos = n_acc + rank;
                    if (pos < MAX_DET) {
                        abox[pos] = cbox[tid]; aarea[pos] = carea[tid];
                        si[pos] = cidx[tid]; ss[pos] = cscore[tid];
                    }
                }
            }
            n_acc += add; if (n_acc > MAX_DET) n_acc = MAX_DET;
            base += m;
            __syncthreads();   // abox visible before next chunk
        }
    }

    const bool part_fb = (!full_fb) && (n_acc < MAX_DET) && (total > inSet);

    if (full_fb || part_fb) {
        // ======== exact fallback: mask-based argmax loop ========
        if (full_fb) {
            n_acc = 0;
            for (int n = tid; n < NN; n += NT) mk[n] = 0;
        } else {
            for (int n = tid; n < NN; n += NT) {
                float4 bbn = bx4[n];
                int s = 0;
                for (int t = 0; t < n_acc; ++t) {
                    float4 A = abox[t];
                    if (iou_ref(A.x, A.y, A.z, A.w, aarea[t],
                                bbn.x, bbn.y, bbn.z, bbn.w) > NMS_T) s = 1;
                }
                mk[n] = (unsigned char)s;
            }
        }
        __syncthreads();

        for (int k = n_acc; k < MAX_DET; ++k) {
            float bv = neg_inf(); int bi = 0x7fffffff;
            for (int n = tid; n < NN; n += NT) {
                if (!mk[n]) {
                    float v = sc[(size_t)n * NC];
                    if (v > SCORE_T && v > bv) { bv = v; bi = n; }
                }
            }
            rv[tid] = bv; ri[tid] = bi;
            __syncthreads();
            for (int s = NT / 2; s > 0; s >>= 1) {
                if (tid < s) {
                    float ov = rv[tid + s]; int oi = ri[tid + s];
                    if (ov > rv[tid] || (ov == rv[tid] && oi < ri[tid])) { rv[tid] = ov; ri[tid] = oi; }
                }
                __syncthreads();
            }
            float mval = rv[0]; int midx = ri[0];
            if (mval == neg_inf()) {
                for (int kk = k + tid; kk < MAX_DET; kk += NT) { si[kk] = 0; ss[kk] = neg_inf(); }
                break;
            }
            if (tid == 0) {
                si[k] = midx; ss[k] = mval;
                float4 sb = bx4[midx];
                sboxsh[0] = sb.x; sboxsh[1] = sb.y; sboxsh[2] = sb.z; sboxsh[3] = sb.w;
                sboxsh[4] = __fmul_rn(__fsub_rn(sb.z, sb.x), __fsub_rn(sb.w, sb.y));
            }
            __syncthreads();
            float ax1 = sboxsh[0], ay1 = sboxsh[1], ax2 = sboxsh[2], ay2 = sboxsh[3];
            float area_a = sboxsh[4];
            for (int n = tid; n < NN; n += NT) {
                float4 bbn = bx4[n];
                if (iou_ref(ax1, ay1, ax2, ay2, area_a,
                            bbn.x, bbn.y, bbn.z, bbn.w) > NMS_T) mk[n] = 1;
            }
            __syncthreads();
        }
    } else {
        for (int kk = n_acc + tid; kk < MAX_DET; kk += NT) { si[kk] = 0; ss[kk] = neg_inf(); }
    }
}

// ---------------- Kernel 2: per-image top-300 + gather -------------------
__global__ __launch_bounds__(NT) void topk_kernel(
    const float* __restrict__ boxes,
    const float* __restrict__ other,
    const int* __restrict__ sel_idx,
    const float* __restrict__ sel_score,
    float* __restrict__ out)
{
    const int b = blockIdx.x;
    const int tid = threadIdx.x;
    const int NCAND = NC * MAX_DET;       // 2400
    __shared__ u64 keys[4096];

    for (int m = tid; m < 4096; m += NT) {
        u64 key = 0ull;
        if (m < NCAND) {
            float v = sel_score[b * NCAND + m];
            unsigned u = __float_as_uint(v);
            u ^= (u & 0x80000000u) ? 0xFFFFFFFFu : 0x80000000u;
            key = ((u64)u << 32) | (unsigned)(~(unsigned)m);
        }
        keys[m] = key;
    }
    __syncthreads();

    for (int k = 2; k <= 4096; k <<= 1) {
        for (int j = k >> 1; j > 0; j >>= 1) {
            for (int p = tid; p < 2048; p += NT) {
                int i = 2 * p - (p & (j - 1));
                int ix = i + j;
                bool dir = ((i & k) == 0);
                u64 a = keys[i], bq = keys[ix];
                if ((a < bq) == dir) { keys[i] = bq; keys[ix] = a; }
            }
            __syncthreads();
        }
    }

    const float4* bx4 = (const float4*)(boxes + (size_t)b * NN * 4);
    const float*  ot  = other + (size_t)b * NN * ND;
    float* ob = out;
    float* os = out + NB * MAX_DET * 4;
    float* ol = os + NB * MAX_DET;
    float* oo = ol + NB * MAX_DET;

    for (int k = tid; k < MAX_DET; k += NT) {
        u64 key = keys[k];
        unsigned u = (unsigned)(key >> 32);
        unsigned uo = (u & 0x80000000u) ? (u ^ 0x80000000u) : (u ^ 0xFFFFFFFFu);
        float score = __uint_as_float(uo);
        bool valid = isfinite(score);
        float b0=-1.f,b1=-1.f,b2=-1.f,b3=-1.f,scv=-1.f,lab=-1.f,o0=-1.f,o1=-1.f;
        if (valid) {
            int m = (int)(~(unsigned)key);
            int c = m / MAX_DET, slot = m - c * MAX_DET;
            int n = sel_idx[(b * NC + c) * MAX_DET + slot];
            float4 bb = bx4[n];
            b0 = bb.x; b1 = bb.y; b2 = bb.z; b3 = bb.w;
            scv = score; lab = (float)c;
            o0 = ot[n * ND + 0]; o1 = ot[n * ND + 1];
        }
        int base = b * MAX_DET + k;
        ob[base * 4 + 0] = b0; ob[base * 4 + 1] = b1;
        ob[base * 4 + 2] = b2; ob[base * 4 + 3] = b3;
        os[base] = scv; ol[base] = lab;
        oo[base * 2 + 0] = o0; oo[base * 2 + 1] = o1;
    }
}

extern "C" void kernel_launch(void* const* d_in, const int* in_sizes, int n_in,
                              void* d_out, int out_size, void* d_ws, size_t ws_size,
                              hipStream_t stream) {
    const float* boxes = (const float*)d_in[0];
    const float* cls   = (const float*)d_in[1];
    const float* other = (const float*)d_in[2];
    float* out = (float*)d_out;

    unsigned char* mask = (unsigned char*)d_ws;
    char* p = (char*)d_ws + (size_t)NB * NC * NN;
    int* sel_idx = (int*)p;
    float* sel_score = (float*)(p + (size_t)NB * NC * MAX_DET * sizeof(int));

    nms_fast<<<NB * NC, NT, 0, stream>>>(boxes, cls, mask, sel_idx, sel_score);
    topk_kernel<<<NB, NT, 0, stream>>>(boxes, other, sel_idx, sel_score, out);
}